// Round 18
// baseline (79.170 us; speedup 1.0000x reference)
//
#include <hip/hip_runtime.h>
#include <hip/hip_bf16.h>

#define NN 1024
#define BB 8
#define HH 8
#define FF 64
#define HF 512
#define KT 128

typedef unsigned short ushortT;

__device__ __forceinline__ ushortT f2bf(float f) {
    __hip_bfloat16 h = __float2bfloat16(f);
    return *(ushortT*)&h;
}
__device__ __forceinline__ float bf2f_u(ushortT u) {
    return __uint_as_float((unsigned)u << 16);
}

// ---------------- K1: fused prep (785 blocks)
__global__ void __launch_bounds__(256) k_prep(
    const float* __restrict__ lab, const float* __restrict__ vis,
    const float* __restrict__ adj, const float* __restrict__ Wm,
    const float* __restrict__ a_src, const float* __restrict__ a_dst,
    ushortT* __restrict__ whb, float* __restrict__ whv2, float* __restrict__ bvp,
    float* __restrict__ es, float* __restrict__ ed, float* __restrict__ edT,
    int* __restrict__ list, int* __restrict__ cnt, float* __restrict__ outp)
{
    int bx = blockIdx.x, t = threadIdx.x;
    __shared__ float sh[1024];
    __shared__ float whs[1024];
    if (bx < 512) {
        int np = bx >> 1, ch = bx & 1, n0 = np * 4;
        #pragma unroll
        for (int nd = 0; nd < 4; ++nd)
            sh[nd * 256 + t] = lab[(n0 + nd) * 256 + t];
        __syncthreads();
        float a0 = 0.f, a1 = 0.f, a2 = 0.f, a3 = 0.f;
        const float* wp = Wm + ch * 256 + t;
        #pragma unroll 8
        for (int i = 0; i < 256; ++i) {
            float w = wp[(size_t)i * HF];
            a0 += sh[i] * w;
            a1 += sh[256 + i] * w;
            a2 += sh[512 + i] * w;
            a3 += sh[768 + i] * w;
        }
        int cb = ch * 256 + t;
        whb[(size_t)(n0 + 0) * HF + cb] = f2bf(a0);
        whb[(size_t)(n0 + 1) * HF + cb] = f2bf(a1);
        whb[(size_t)(n0 + 2) * HF + cb] = f2bf(a2);
        whb[(size_t)(n0 + 3) * HF + cb] = f2bf(a3);
        whs[t] = a0; whs[256 + t] = a1; whs[512 + t] = a2; whs[768 + t] = a3;
        __syncthreads();
        if (t < 32) {
            int nd = t >> 3, rest = t & 7, hl = rest >> 1, sd = rest & 1;
            int h = ch * 4 + hl;
            const float* av = (sd ? a_dst : a_src) + h * FF;
            const float* wr = whs + nd * 256 + hl * FF;
            float s = 0.f;
            #pragma unroll
            for (int f = 0; f < FF; ++f) s += wr[f] * av[f];
            int n = n0 + nd;
            if (sd) { ed[n * HH + h] = s; edT[h * NN + n] = s; }
            else es[n * HH + h] = s;
        }
    } else if (bx < 528) {
        int id = bx - 512, b = id >> 1, kh = id & 1;
        if (t < 256) sh[t] = vis[b * 512 + kh * 256 + t];
        __syncthreads();
        float a0 = 0.f, a1 = 0.f;
        const float* wp = Wm + (size_t)(256 + kh * 256) * HF;
        #pragma unroll 4
        for (int i = 0; i < 256; ++i) {
            float xv = sh[i];
            a0 += xv * wp[(size_t)i * HF + t];
            a1 += xv * wp[(size_t)i * HF + t + 256];
        }
        float* dst = whv2 + (size_t)(kh * BB + b) * HF;
        dst[t] = a0; dst[t + 256] = a1;
        whs[t] = a0; whs[256 + t] = a1;
        __syncthreads();
        if (t < 8) {
            const float* as = a_src + t * FF;
            const float* ad = a_dst + t * FF;
            const float* wr = whs + t * FF;
            float s = 0.f;
            #pragma unroll 8
            for (int f = 0; f < FF; ++f) s += wr[f] * (as[f] + ad[f]);
            bvp[kh * 64 + b * 8 + t] = s;
        }
    } else if (bx < 784) {
        int id = bx - 528;
        int i = id * 4 + (t >> 6), lane = t & 63;
        int base = 0;
        for (int c = 0; c < 16; ++c) {
            int j = c * 64 + lane;
            bool pres = adj[(size_t)i * NN + j] > 0.f;
            unsigned long long m = __ballot(pres);
            int pos = __popcll(m & ((1ull << lane) - 1ull));
            if (pres) list[i * NN + base + pos] = j;
            base += __popcll(m);
        }
        if (lane == 0) cnt[i] = base;
    } else {
        float4 z; z.x = 0.f; z.y = 0.f; z.z = 0.f; z.w = 0.f;
        float4* oo = (float4*)outp;
        #pragma unroll
        for (int q = 0; q < 4; ++q) oo[q * 256 + t] = z;
    }
}

// ---------------- K2: attention — LDS-staged gathers (whs batches + edl), wave-parallel k
__global__ void __launch_bounds__(256) k_attn(
    const ushortT* __restrict__ whb, const float* __restrict__ whv2,
    const float* __restrict__ es, const float* __restrict__ ed,
    const float* __restrict__ edT, const float* __restrict__ bvp,
    const int* __restrict__ list, const int* __restrict__ cnt,
    const float* __restrict__ pool_q,
    ushortT* __restrict__ xoutb, float* __restrict__ sch)
{
    int i = blockIdx.x, z = blockIdx.y, t = threadIdx.x;
    int nn = cnt[i];

    __shared__ float att[KT * 32];       // 16 KB; reused as merge buffer
    __shared__ ushortT whs[32 * 256];    // 16 KB staged wh rows (z-half)
    __shared__ float edl[KT * 4];        // 2 KB staged ed rows (z-half)
    __shared__ int jl[KT];
    __shared__ float base_s[32], M_s[32], inv_s[32];
    __shared__ float red[8][32];
    __shared__ float edmax_z[4];

    // prologue: per-head global ed max
    {
        int hl = t >> 6, h = z * 4 + hl;
        const float* col = edT + h * NN;
        float m = -1e30f;
        #pragma unroll
        for (int g = 0; g < 16; ++g) m = fmaxf(m, col[(t & 63) + g * 64]);
        #pragma unroll
        for (int off = 32; off > 0; off >>= 1) m = fmaxf(m, __shfl_down(m, off));
        if ((t & 63) == 0) edmax_z[hl] = m;
    }
    __syncthreads();
    if (t < 32) {
        int hl = t >> 3, b = t & 7, h = z * 4 + hl;
        float base = es[i * HH + h] + bvp[b * 8 + h] + bvp[64 + b * 8 + h];
        base_s[t] = base;
        float mv = base + edmax_z[hl];       // >= any neighbor pre-leaky e
        M_s[t] = mv > 0.f ? mv : 0.2f * mv;  // leaky monotone -> valid upper bound
    }
    __syncthreads();

    int p = t & 31;
    float basev = base_s[p], Mv = M_s[p];
    float ssum = 0.f;

    int wid = t >> 6, tf = t & 63;
    int f0 = z * 256 + 4 * tf;         // 4 consecutive feats, same head
    int hl8 = (tf >> 4) * 8;           // head-local * 8
    float ac[32];                      // ac[f*8+b]
    #pragma unroll
    for (int q = 0; q < 32; ++q) ac[q] = 0.f;

    for (int c0 = 0; c0 < nn; c0 += KT) {
        int kc = min(KT, nn - c0);
        __syncthreads();               // protect att/jl/edl/whs reuse across chunks
        if (t < kc) {
            int jv = list[(size_t)i * NN + c0 + t];
            jl[t] = jv;
            float4 v = *(const float4*)&ed[(size_t)jv * HH + z * 4];
            *(float4*)&edl[t * 4] = v;
        }
        __syncthreads();
        // exp phase: pure LDS
        for (int k = t >> 5; k < kc; k += 8) {
            float e = basev + edl[(k << 2) + (p >> 3)];
            e = e > 0.f ? e : 0.2f * e;
            float pe = __expf(e - Mv);
            ssum += pe;
            att[k * 32 + p] = pe;
        }
        // batched staging + compute
        for (int b0 = 0; b0 < kc; b0 += 32) {
            int bcnt = min(32, kc - b0);
            __syncthreads();           // att ready / previous batch compute done
            #pragma unroll
            for (int r = 0; r < 8; ++r) {
                int idx = r * 256 + t;
                int row = idx >> 6, c4 = idx & 63;
                if (row < bcnt) {
                    ushort4 u = *(const ushort4*)&whb[(size_t)jl[b0 + row] * HF + z * 256 + c4 * 4];
                    *(ushort4*)&whs[row * 256 + c4 * 4] = u;
                }
            }
            __syncthreads();
            for (int k = wid; k < bcnt; k += 4) {
                const ushort4 u = *(const ushort4*)&whs[k * 256 + 4 * tf];
                float r0 = bf2f_u(u.x), r1 = bf2f_u(u.y);
                float r2 = bf2f_u(u.z), r3 = bf2f_u(u.w);
                const float4 aA = *(const float4*)&att[(b0 + k) * 32 + hl8];
                const float4 aB = *(const float4*)&att[(b0 + k) * 32 + hl8 + 4];
                ac[0]  += aA.x * r0; ac[8]  += aA.x * r1; ac[16] += aA.x * r2; ac[24] += aA.x * r3;
                ac[1]  += aA.y * r0; ac[9]  += aA.y * r1; ac[17] += aA.y * r2; ac[25] += aA.y * r3;
                ac[2]  += aA.z * r0; ac[10] += aA.z * r1; ac[18] += aA.z * r2; ac[26] += aA.z * r3;
                ac[3]  += aA.w * r0; ac[11] += aA.w * r1; ac[19] += aA.w * r2; ac[27] += aA.w * r3;
                ac[4]  += aB.x * r0; ac[12] += aB.x * r1; ac[20] += aB.x * r2; ac[28] += aB.x * r3;
                ac[5]  += aB.y * r0; ac[13] += aB.y * r1; ac[21] += aB.y * r2; ac[29] += aB.y * r3;
                ac[6]  += aB.z * r0; ac[14] += aB.z * r1; ac[22] += aB.z * r2; ac[30] += aB.z * r3;
                ac[7]  += aB.w * r0; ac[15] += aB.w * r1; ac[23] += aB.w * r2; ac[31] += aB.w * r3;
            }
        }
    }

    // ---- reductions: softmax sums + 4-way accumulator merge (conflict-free layout) ----
    __syncthreads();                   // all att reads done
    red[t >> 5][p] = ssum;
    float* mrg = att;                  // mrg[q*64+tf]: lanes hit consecutive banks
    if (wid == 3) {
        #pragma unroll
        for (int q = 0; q < 32; ++q) mrg[q * 64 + tf] = ac[q];
    }
    __syncthreads();
    if (t < 32) {
        float s = 0.f;
        #pragma unroll
        for (int g = 0; g < 8; ++g) s += red[g][t];
        inv_s[t] = 1.0f / s;
    }
    if (wid == 2) {
        #pragma unroll
        for (int q = 0; q < 32; ++q) mrg[q * 64 + tf] += ac[q];
    }
    __syncthreads();
    if (wid == 1) {
        #pragma unroll
        for (int q = 0; q < 32; ++q) mrg[q * 64 + tf] += ac[q];
    }
    __syncthreads();

    if (wid == 0) {
        #pragma unroll
        for (int q = 0; q < 32; ++q) ac[q] += mrg[q * 64 + tf];
        int hl = tf >> 4;
        const float4 pq4 = *(const float4*)&pool_q[f0];
        #pragma unroll
        for (int b = 0; b < BB; ++b) {
            float iv = inv_s[hl * 8 + b];
            const float4 wva = *(const float4*)&whv2[(size_t)b * HF + f0];
            const float4 wvb = *(const float4*)&whv2[(size_t)(BB + b) * HF + f0];
            float o0 = ac[b]      * iv + wva.x + wvb.x;
            float o1 = ac[8 + b]  * iv + wva.y + wvb.y;
            float o2 = ac[16 + b] * iv + wva.z + wvb.z;
            float o3 = ac[24 + b] * iv + wva.w + wvb.w;
            o0 = o0 > 0.f ? o0 : (__expf(o0) - 1.f);
            o1 = o1 > 0.f ? o1 : (__expf(o1) - 1.f);
            o2 = o2 > 0.f ? o2 : (__expf(o2) - 1.f);
            o3 = o3 > 0.f ? o3 : (__expf(o3) - 1.f);
            ushort4 ov;
            ov.x = f2bf(o0); ov.y = f2bf(o1); ov.z = f2bf(o2); ov.w = f2bf(o3);
            *(ushort4*)&xoutb[((size_t)b * NN + i) * HF + f0] = ov;
            float sp = o0 * pq4.x + o1 * pq4.y + o2 * pq4.z + o3 * pq4.w;
            #pragma unroll
            for (int off = 32; off > 0; off >>= 1) sp += __shfl_down(sp, off);
            if (t == 0) sch[(z * BB + b) * NN + i] = sp;
        }
    }
}

// ---------------- K3: fused node softmax + pool + FC partial (32 x 16-feat slices)
__global__ void __launch_bounds__(256) k_tail(const float* __restrict__ sch,
    const ushortT* __restrict__ xoutb, const float* __restrict__ fcW,
    const float* __restrict__ fcb, float* __restrict__ out)
{
    int q = blockIdx.x, b = blockIdx.y, t = threadIdx.x;
    int lane = t & 63, wid = t >> 6;
    __shared__ float red[4];
    __shared__ float sM, sI;
    __shared__ float wl[NN];
    __shared__ float part[16][16];
    __shared__ float pl[16];

    float v[4], e[4];
    float mx = -1e30f;
    #pragma unroll
    for (int qq = 0; qq < 4; ++qq) {
        int n = qq * 256 + t;
        v[qq] = sch[b * NN + n] + sch[(BB + b) * NN + n];
        mx = fmaxf(mx, v[qq]);
    }
    #pragma unroll
    for (int off = 32; off > 0; off >>= 1) mx = fmaxf(mx, __shfl_down(mx, off));
    if (lane == 0) red[wid] = mx;
    __syncthreads();
    if (t == 0) sM = fmaxf(fmaxf(red[0], red[1]), fmaxf(red[2], red[3]));
    __syncthreads();
    float sMv = sM;
    float sm = 0.f;
    #pragma unroll
    for (int qq = 0; qq < 4; ++qq) { e[qq] = __expf(v[qq] - sMv); sm += e[qq]; }
    #pragma unroll
    for (int off = 32; off > 0; off >>= 1) sm += __shfl_down(sm, off);
    __syncthreads();
    if (lane == 0) red[wid] = sm;
    __syncthreads();
    if (t == 0) sI = 1.0f / (red[0] + red[1] + red[2] + red[3]);
    __syncthreads();
    float sIv = sI;
    #pragma unroll
    for (int qq = 0; qq < 4; ++qq) wl[qq * 256 + t] = e[qq] * sIv;
    __syncthreads();

    // pool feature-slice q (16 feats) over all nodes: fl = t&15, node-group ng = t>>4
    int fl = t & 15, ng = t >> 4;
    const ushortT* xb = xoutb + (size_t)b * NN * HF + q * 16 + fl;
    float acc0 = 0.f, acc1 = 0.f;
    #pragma unroll 8
    for (int n0 = 0; n0 < NN; n0 += 32) {
        int na = n0 + ng, nb2 = n0 + 16 + ng;
        acc0 += wl[na]  * bf2f_u(xb[(size_t)na  * HF]);
        acc1 += wl[nb2] * bf2f_u(xb[(size_t)nb2 * HF]);
    }
    part[ng][fl] = acc0 + acc1;
    __syncthreads();
    if (t < 16) {
        float s = 0.f;
        #pragma unroll
        for (int g = 0; g < 16; ++g) s += part[g][t];
        pl[t] = s;
    }
    __syncthreads();

    // FC partial: fcW rows q*16..q*16+15
    int f0 = 2 * t;
    float ax = 0.f, ay = 0.f;
    if (q == 0) { ax = fcb[f0]; ay = fcb[f0 + 1]; }
    #pragma unroll
    for (int kk = 0; kk < 16; ++kk) {
        float pv = pl[kk];
        const float2 w2 = *(const float2*)&fcW[(size_t)(q * 16 + kk) * HF + f0];
        ax += pv * w2.x; ay += pv * w2.y;
    }
    atomicAdd(&out[b * HF + f0], ax);
    atomicAdd(&out[b * HF + f0 + 1], ay);
}

extern "C" void kernel_launch(void* const* d_in, const int* in_sizes, int n_in,
                              void* d_out, int out_size, void* d_ws, size_t ws_size,
                              hipStream_t stream) {
    const float* vis   = (const float*)d_in[0];
    const float* lab   = (const float*)d_in[1];
    const float* adj   = (const float*)d_in[2];
    const float* Wm    = (const float*)d_in[3];
    const float* a_src = (const float*)d_in[4];
    const float* a_dst = (const float*)d_in[5];
    const float* pq    = (const float*)d_in[6];
    const float* fcW   = (const float*)d_in[7];
    const float* fcb   = (const float*)d_in[8];
    float* out = (float*)d_out;

    char* w = (char*)d_ws;
    ushortT* whb  = (ushortT*)w; w += (size_t)NN * HF * 2;      // 1 MB (bf16)
    float* whv2   = (float*)w;   w += (size_t)2 * BB * HF * 4;  // 32 KB
    float* bvp    = (float*)w;   w += 2 * 64 * 4;
    float* es     = (float*)w;   w += (size_t)NN * HH * 4;
    float* ed     = (float*)w;   w += (size_t)NN * HH * 4;
    float* edT    = (float*)w;   w += (size_t)HH * NN * 4;
    int*   nlist  = (int*)w;     w += (size_t)NN * NN * 4;      // 4 MB
    int*   ncnt   = (int*)w;     w += (size_t)NN * 4;
    ushortT* xoutb = (ushortT*)w; w += (size_t)BB * NN * HF * 2; // 8 MB (bf16)
    float* sch    = (float*)w;   w += (size_t)2 * BB * NN * 4;  // 64 KB

    k_prep<<<785, 256, 0, stream>>>(lab, vis, adj, Wm, a_src, a_dst,
                                    whb, whv2, bvp, es, ed, edT, nlist, ncnt, out);
    k_attn<<<dim3(NN, 2), 256, 0, stream>>>(whb, whv2, es, ed, edT, bvp,
                                            nlist, ncnt, pq, xoutb, sch);
    k_tail<<<dim3(32, BB), 256, 0, stream>>>(sch, xoutb, fcW, fcb, out);
}

// Round 19
// 72.717 us; speedup vs baseline: 1.0887x; 1.0887x over previous
//
#include <hip/hip_runtime.h>
#include <hip/hip_bf16.h>

#define NN 1024
#define BB 8
#define HH 8
#define FF 64
#define HF 512
#define KT 128

typedef unsigned short ushortT;

__device__ __forceinline__ ushortT f2bf(float f) {
    __hip_bfloat16 h = __float2bfloat16(f);
    return *(ushortT*)&h;
}
__device__ __forceinline__ float bf2f_u(ushortT u) {
    return __uint_as_float((unsigned)u << 16);
}

// ---------------- K1: fused prep (785 blocks)
//  bx 0..511  : wh GEMM full-K (4 nodes x 256-col half) + es/ed/edT epilogue
//  bx 512..527: whv2 K-half partials + bv partials
//  bx 528..783: adjacency compaction (4 rows/block)
//  bx 784     : zero out
__global__ void __launch_bounds__(256) k_prep(
    const float* __restrict__ lab, const float* __restrict__ vis,
    const float* __restrict__ adj, const float* __restrict__ Wm,
    const float* __restrict__ a_src, const float* __restrict__ a_dst,
    ushortT* __restrict__ whb, float* __restrict__ whv2, float* __restrict__ bvp,
    float* __restrict__ es, float* __restrict__ ed, float* __restrict__ edT,
    int* __restrict__ list, int* __restrict__ cnt, float* __restrict__ outp)
{
    int bx = blockIdx.x, t = threadIdx.x;
    __shared__ float sh[1024];
    __shared__ float whs[1024];
    if (bx < 512) {
        int np = bx >> 1, ch = bx & 1, n0 = np * 4;
        #pragma unroll
        for (int nd = 0; nd < 4; ++nd)
            sh[nd * 256 + t] = lab[(n0 + nd) * 256 + t];
        __syncthreads();
        float a0 = 0.f, a1 = 0.f, a2 = 0.f, a3 = 0.f;
        const float* wp = Wm + ch * 256 + t;
        #pragma unroll 8
        for (int i = 0; i < 256; ++i) {
            float w = wp[(size_t)i * HF];
            a0 += sh[i] * w;
            a1 += sh[256 + i] * w;
            a2 += sh[512 + i] * w;
            a3 += sh[768 + i] * w;
        }
        int cb = ch * 256 + t;
        whb[(size_t)(n0 + 0) * HF + cb] = f2bf(a0);
        whb[(size_t)(n0 + 1) * HF + cb] = f2bf(a1);
        whb[(size_t)(n0 + 2) * HF + cb] = f2bf(a2);
        whb[(size_t)(n0 + 3) * HF + cb] = f2bf(a3);
        whs[t] = a0; whs[256 + t] = a1; whs[512 + t] = a2; whs[768 + t] = a3;
        __syncthreads();
        if (t < 32) {
            int nd = t >> 3, rest = t & 7, hl = rest >> 1, sd = rest & 1;
            int h = ch * 4 + hl;
            const float* av = (sd ? a_dst : a_src) + h * FF;
            const float* wr = whs + nd * 256 + hl * FF;
            float s = 0.f;
            #pragma unroll
            for (int f = 0; f < FF; ++f) s += wr[f] * av[f];
            int n = n0 + nd;
            if (sd) { ed[n * HH + h] = s; edT[h * NN + n] = s; }
            else es[n * HH + h] = s;
        }
    } else if (bx < 528) {
        int id = bx - 512, b = id >> 1, kh = id & 1;
        if (t < 256) sh[t] = vis[b * 512 + kh * 256 + t];
        __syncthreads();
        float a0 = 0.f, a1 = 0.f;
        const float* wp = Wm + (size_t)(256 + kh * 256) * HF;
        #pragma unroll 4
        for (int i = 0; i < 256; ++i) {
            float xv = sh[i];
            a0 += xv * wp[(size_t)i * HF + t];
            a1 += xv * wp[(size_t)i * HF + t + 256];
        }
        float* dst = whv2 + (size_t)(kh * BB + b) * HF;
        dst[t] = a0; dst[t + 256] = a1;
        whs[t] = a0; whs[256 + t] = a1;
        __syncthreads();
        if (t < 8) {
            const float* as = a_src + t * FF;
            const float* ad = a_dst + t * FF;
            const float* wr = whs + t * FF;
            float s = 0.f;
            #pragma unroll 8
            for (int f = 0; f < FF; ++f) s += wr[f] * (as[f] + ad[f]);
            bvp[kh * 64 + b * 8 + t] = s;
        }
    } else if (bx < 784) {
        int id = bx - 528;
        int i = id * 4 + (t >> 6), lane = t & 63;
        int base = 0;
        for (int c = 0; c < 16; ++c) {
            int j = c * 64 + lane;
            bool pres = adj[(size_t)i * NN + j] > 0.f;
            unsigned long long m = __ballot(pres);
            int pos = __popcll(m & ((1ull << lane) - 1ull));
            if (pres) list[i * NN + base + pos] = j;
            base += __popcll(m);
        }
        if (lane == 0) cnt[i] = base;
    } else {
        float4 z; z.x = 0.f; z.y = 0.f; z.z = 0.f; z.w = 0.f;
        float4* oo = (float4*)outp;
        #pragma unroll
        for (int q = 0; q < 4; ++q) oo[q * 256 + t] = z;
    }
}

// ---------------- K2: attention — 4 feats/thread, wave-parallel k, conflict-free merge
__global__ void __launch_bounds__(256) k_attn(
    const ushortT* __restrict__ whb, const float* __restrict__ whv2,
    const float* __restrict__ es, const float* __restrict__ ed,
    const float* __restrict__ edT, const float* __restrict__ bvp,
    const int* __restrict__ list, const int* __restrict__ cnt,
    const float* __restrict__ pool_q,
    ushortT* __restrict__ xoutb, float* __restrict__ sch)
{
    int i = blockIdx.x, z = blockIdx.y, t = threadIdx.x;
    int nn = cnt[i];

    __shared__ float att[KT * 32];     // 16 KB; reused as merge buffer
    __shared__ int jl[KT];
    __shared__ float base_s[32], M_s[32], inv_s[32];
    __shared__ float red[8][32];
    __shared__ float edmax_z[4];

    // prologue: per-head global ed max
    {
        int hl = t >> 6, h = z * 4 + hl;
        const float* col = edT + h * NN;
        float m = -1e30f;
        #pragma unroll
        for (int g = 0; g < 16; ++g) m = fmaxf(m, col[(t & 63) + g * 64]);
        #pragma unroll
        for (int off = 32; off > 0; off >>= 1) m = fmaxf(m, __shfl_down(m, off));
        if ((t & 63) == 0) edmax_z[hl] = m;
    }
    __syncthreads();
    if (t < 32) {
        int hl = t >> 3, b = t & 7, h = z * 4 + hl;
        float base = es[i * HH + h] + bvp[b * 8 + h] + bvp[64 + b * 8 + h];
        base_s[t] = base;
        float mv = base + edmax_z[hl];       // >= any neighbor pre-leaky e
        M_s[t] = mv > 0.f ? mv : 0.2f * mv;  // leaky monotone -> valid upper bound
    }
    __syncthreads();

    int p = t & 31;
    int hp = z * 4 + (p >> 3);
    float basev = base_s[p], Mv = M_s[p];
    float ssum = 0.f;

    int wid = t >> 6, tf = t & 63;
    int f0 = z * 256 + 4 * tf;         // 4 consecutive feats, same head
    int hl8 = (tf >> 4) * 8;           // head-local * 8
    float ac[32];                      // ac[f*8+b]
    #pragma unroll
    for (int q = 0; q < 32; ++q) ac[q] = 0.f;

    for (int c0 = 0; c0 < nn; c0 += KT) {
        int kc = min(KT, nn - c0);
        __syncthreads();               // protect att/jl reuse
        if (t < kc) jl[t] = list[(size_t)i * NN + c0 + t];
        __syncthreads();
        for (int k = t >> 5; k < kc; k += 8) {
            int j = jl[k];
            float e = basev + ed[j * HH + hp];
            e = e > 0.f ? e : 0.2f * e;
            float pe = __expf(e - Mv);
            ssum += pe;
            att[k * 32 + p] = pe;
        }
        __syncthreads();
        #pragma unroll 2
        for (int k = wid; k < kc; k += 4) {
            int row = jl[k];
            const ushort4 u = *(const ushort4*)&whb[(size_t)row * HF + f0];
            float r0 = bf2f_u(u.x), r1 = bf2f_u(u.y);
            float r2 = bf2f_u(u.z), r3 = bf2f_u(u.w);
            const float4 aA = *(const float4*)&att[k * 32 + hl8];
            const float4 aB = *(const float4*)&att[k * 32 + hl8 + 4];
            ac[0]  += aA.x * r0; ac[8]  += aA.x * r1; ac[16] += aA.x * r2; ac[24] += aA.x * r3;
            ac[1]  += aA.y * r0; ac[9]  += aA.y * r1; ac[17] += aA.y * r2; ac[25] += aA.y * r3;
            ac[2]  += aA.z * r0; ac[10] += aA.z * r1; ac[18] += aA.z * r2; ac[26] += aA.z * r3;
            ac[3]  += aA.w * r0; ac[11] += aA.w * r1; ac[19] += aA.w * r2; ac[27] += aA.w * r3;
            ac[4]  += aB.x * r0; ac[12] += aB.x * r1; ac[20] += aB.x * r2; ac[28] += aB.x * r3;
            ac[5]  += aB.y * r0; ac[13] += aB.y * r1; ac[21] += aB.y * r2; ac[29] += aB.y * r3;
            ac[6]  += aB.z * r0; ac[14] += aB.z * r1; ac[22] += aB.z * r2; ac[30] += aB.z * r3;
            ac[7]  += aB.w * r0; ac[15] += aB.w * r1; ac[23] += aB.w * r2; ac[31] += aB.w * r3;
        }
    }

    // ---- reductions: softmax sums + 4-way accumulator merge (conflict-free layout) ----
    __syncthreads();                   // all att reads done
    red[t >> 5][p] = ssum;
    float* mrg = att;                  // mrg[q*64+tf]: lanes hit consecutive banks
    if (wid == 3) {
        #pragma unroll
        for (int q = 0; q < 32; ++q) mrg[q * 64 + tf] = ac[q];
    }
    __syncthreads();
    if (t < 32) {
        float s = 0.f;
        #pragma unroll
        for (int g = 0; g < 8; ++g) s += red[g][t];
        inv_s[t] = 1.0f / s;
    }
    if (wid == 2) {
        #pragma unroll
        for (int q = 0; q < 32; ++q) mrg[q * 64 + tf] += ac[q];
    }
    __syncthreads();
    if (wid == 1) {
        #pragma unroll
        for (int q = 0; q < 32; ++q) mrg[q * 64 + tf] += ac[q];
    }
    __syncthreads();

    if (wid == 0) {
        #pragma unroll
        for (int q = 0; q < 32; ++q) ac[q] += mrg[q * 64 + tf];
        int hl = tf >> 4;
        const float4 pq4 = *(const float4*)&pool_q[f0];
        #pragma unroll
        for (int b = 0; b < BB; ++b) {
            float iv = inv_s[hl * 8 + b];
            const float4 wva = *(const float4*)&whv2[(size_t)b * HF + f0];
            const float4 wvb = *(const float4*)&whv2[(size_t)(BB + b) * HF + f0];
            float o0 = ac[b]      * iv + wva.x + wvb.x;
            float o1 = ac[8 + b]  * iv + wva.y + wvb.y;
            float o2 = ac[16 + b] * iv + wva.z + wvb.z;
            float o3 = ac[24 + b] * iv + wva.w + wvb.w;
            o0 = o0 > 0.f ? o0 : (__expf(o0) - 1.f);
            o1 = o1 > 0.f ? o1 : (__expf(o1) - 1.f);
            o2 = o2 > 0.f ? o2 : (__expf(o2) - 1.f);
            o3 = o3 > 0.f ? o3 : (__expf(o3) - 1.f);
            ushort4 ov;
            ov.x = f2bf(o0); ov.y = f2bf(o1); ov.z = f2bf(o2); ov.w = f2bf(o3);
            *(ushort4*)&xoutb[((size_t)b * NN + i) * HF + f0] = ov;
            float sp = o0 * pq4.x + o1 * pq4.y + o2 * pq4.z + o3 * pq4.w;
            #pragma unroll
            for (int off = 32; off > 0; off >>= 1) sp += __shfl_down(sp, off);
            if (t == 0) sch[(z * BB + b) * NN + i] = sp;
        }
    }
}

// ---------------- K3: fused node softmax + pool + FC partial (32 x 16-feat slices)
__global__ void __launch_bounds__(256) k_tail(const float* __restrict__ sch,
    const ushortT* __restrict__ xoutb, const float* __restrict__ fcW,
    const float* __restrict__ fcb, float* __restrict__ out)
{
    int q = blockIdx.x, b = blockIdx.y, t = threadIdx.x;
    int lane = t & 63, wid = t >> 6;
    __shared__ float red[4];
    __shared__ float sM, sI;
    __shared__ float wl[NN];
    __shared__ float part[16][16];
    __shared__ float pl[16];

    float v[4], e[4];
    float mx = -1e30f;
    #pragma unroll
    for (int qq = 0; qq < 4; ++qq) {
        int n = qq * 256 + t;
        v[qq] = sch[b * NN + n] + sch[(BB + b) * NN + n];
        mx = fmaxf(mx, v[qq]);
    }
    #pragma unroll
    for (int off = 32; off > 0; off >>= 1) mx = fmaxf(mx, __shfl_down(mx, off));
    if (lane == 0) red[wid] = mx;
    __syncthreads();
    if (t == 0) sM = fmaxf(fmaxf(red[0], red[1]), fmaxf(red[2], red[3]));
    __syncthreads();
    float sMv = sM;
    float sm = 0.f;
    #pragma unroll
    for (int qq = 0; qq < 4; ++qq) { e[qq] = __expf(v[qq] - sMv); sm += e[qq]; }
    #pragma unroll
    for (int off = 32; off > 0; off >>= 1) sm += __shfl_down(sm, off);
    __syncthreads();
    if (lane == 0) red[wid] = sm;
    __syncthreads();
    if (t == 0) sI = 1.0f / (red[0] + red[1] + red[2] + red[3]);
    __syncthreads();
    float sIv = sI;
    #pragma unroll
    for (int qq = 0; qq < 4; ++qq) wl[qq * 256 + t] = e[qq] * sIv;
    __syncthreads();

    // pool feature-slice q (16 feats) over all nodes: fl = t&15, node-group ng = t>>4
    int fl = t & 15, ng = t >> 4;
    const ushortT* xb = xoutb + (size_t)b * NN * HF + q * 16 + fl;
    float acc0 = 0.f, acc1 = 0.f;
    #pragma unroll 8
    for (int n0 = 0; n0 < NN; n0 += 32) {
        int na = n0 + ng, nb2 = n0 + 16 + ng;
        acc0 += wl[na]  * bf2f_u(xb[(size_t)na  * HF]);
        acc1 += wl[nb2] * bf2f_u(xb[(size_t)nb2 * HF]);
    }
    part[ng][fl] = acc0 + acc1;
    __syncthreads();
    if (t < 16) {
        float s = 0.f;
        #pragma unroll
        for (int g = 0; g < 16; ++g) s += part[g][t];
        pl[t] = s;
    }
    __syncthreads();

    // FC partial: fcW rows q*16..q*16+15
    int f0 = 2 * t;
    float ax = 0.f, ay = 0.f;
    if (q == 0) { ax = fcb[f0]; ay = fcb[f0 + 1]; }
    #pragma unroll
    for (int kk = 0; kk < 16; ++kk) {
        float pv = pl[kk];
        const float2 w2 = *(const float2*)&fcW[(size_t)(q * 16 + kk) * HF + f0];
        ax += pv * w2.x; ay += pv * w2.y;
    }
    atomicAdd(&out[b * HF + f0], ax);
    atomicAdd(&out[b * HF + f0 + 1], ay);
}

extern "C" void kernel_launch(void* const* d_in, const int* in_sizes, int n_in,
                              void* d_out, int out_size, void* d_ws, size_t ws_size,
                              hipStream_t stream) {
    const float* vis   = (const float*)d_in[0];
    const float* lab   = (const float*)d_in[1];
    const float* adj   = (const float*)d_in[2];
    const float* Wm    = (const float*)d_in[3];
    const float* a_src = (const float*)d_in[4];
    const float* a_dst = (const float*)d_in[5];
    const float* pq    = (const float*)d_in[6];
    const float* fcW   = (const float*)d_in[7];
    const float* fcb   = (const float*)d_in[8];
    float* out = (float*)d_out;

    char* w = (char*)d_ws;
    ushortT* whb  = (ushortT*)w; w += (size_t)NN * HF * 2;      // 1 MB (bf16)
    float* whv2   = (float*)w;   w += (size_t)2 * BB * HF * 4;  // 32 KB
    float* bvp    = (float*)w;   w += 2 * 64 * 4;
    float* es     = (float*)w;   w += (size_t)NN * HH * 4;
    float* ed     = (float*)w;   w += (size_t)NN * HH * 4;
    float* edT    = (float*)w;   w += (size_t)HH * NN * 4;
    int*   nlist  = (int*)w;     w += (size_t)NN * NN * 4;      // 4 MB
    int*   ncnt   = (int*)w;     w += (size_t)NN * 4;
    ushortT* xoutb = (ushortT*)w; w += (size_t)BB * NN * HF * 2; // 8 MB (bf16)
    float* sch    = (float*)w;   w += (size_t)2 * BB * NN * 4;  // 64 KB

    k_prep<<<785, 256, 0, stream>>>(lab, vis, adj, Wm, a_src, a_dst,
                                    whb, whv2, bvp, es, ed, edT, nlist, ncnt, out);
    k_attn<<<dim3(NN, 2), 256, 0, stream>>>(whb, whv2, es, ed, edT, bvp,
                                            nlist, ncnt, pq, xoutb, sch);
    k_tail<<<dim3(32, BB), 256, 0, stream>>>(sch, xoutb, fcW, fcb, out);
}

// Round 20
// 68.376 us; speedup vs baseline: 1.1579x; 1.0635x over previous
//
#include <hip/hip_runtime.h>
#include <hip/hip_bf16.h>

#define NN 1024
#define BB 8
#define HH 8
#define FF 64
#define HF 512
#define KT 128

typedef unsigned short ushortT;

__device__ __forceinline__ ushortT f2bf(float f) {
    __hip_bfloat16 h = __float2bfloat16(f);
    return *(ushortT*)&h;
}
__device__ __forceinline__ float bf2f_u(ushortT u) {
    return __uint_as_float((unsigned)u << 16);
}

// ---------------- K1: fused prep (785 blocks)
//  bx 0..511  : wh GEMM full-K (4 nodes x 256-col half) + es/ed/edT epilogue
//  bx 512..527: whv2 K-half partials + bv partials
//  bx 528..783: adjacency compaction (4 rows/block)
//  bx 784     : zero out
__global__ void __launch_bounds__(256) k_prep(
    const float* __restrict__ lab, const float* __restrict__ vis,
    const float* __restrict__ adj, const float* __restrict__ Wm,
    const float* __restrict__ a_src, const float* __restrict__ a_dst,
    ushortT* __restrict__ whb, float* __restrict__ whv2, float* __restrict__ bvp,
    float* __restrict__ es, float* __restrict__ ed, float* __restrict__ edT,
    int* __restrict__ list, int* __restrict__ cnt, float* __restrict__ outp)
{
    int bx = blockIdx.x, t = threadIdx.x;
    __shared__ float sh[1024];
    __shared__ float whs[1024];
    if (bx < 512) {
        int np = bx >> 1, ch = bx & 1, n0 = np * 4;
        #pragma unroll
        for (int nd = 0; nd < 4; ++nd)
            sh[nd * 256 + t] = lab[(n0 + nd) * 256 + t];
        __syncthreads();
        float a0 = 0.f, a1 = 0.f, a2 = 0.f, a3 = 0.f;
        const float* wp = Wm + ch * 256 + t;
        #pragma unroll 8
        for (int i = 0; i < 256; ++i) {
            float w = wp[(size_t)i * HF];
            a0 += sh[i] * w;
            a1 += sh[256 + i] * w;
            a2 += sh[512 + i] * w;
            a3 += sh[768 + i] * w;
        }
        int cb = ch * 256 + t;
        whb[(size_t)(n0 + 0) * HF + cb] = f2bf(a0);
        whb[(size_t)(n0 + 1) * HF + cb] = f2bf(a1);
        whb[(size_t)(n0 + 2) * HF + cb] = f2bf(a2);
        whb[(size_t)(n0 + 3) * HF + cb] = f2bf(a3);
        whs[t] = a0; whs[256 + t] = a1; whs[512 + t] = a2; whs[768 + t] = a3;
        __syncthreads();
        if (t < 32) {
            int nd = t >> 3, rest = t & 7, hl = rest >> 1, sd = rest & 1;
            int h = ch * 4 + hl;
            const float* av = (sd ? a_dst : a_src) + h * FF;
            const float* wr = whs + nd * 256 + hl * FF;
            float s = 0.f;
            #pragma unroll
            for (int f = 0; f < FF; ++f) s += wr[f] * av[f];
            int n = n0 + nd;
            if (sd) { ed[n * HH + h] = s; edT[h * NN + n] = s; }
            else es[n * HH + h] = s;
        }
    } else if (bx < 528) {
        int id = bx - 512, b = id >> 1, kh = id & 1;
        if (t < 256) sh[t] = vis[b * 512 + kh * 256 + t];
        __syncthreads();
        float a0 = 0.f, a1 = 0.f;
        const float* wp = Wm + (size_t)(256 + kh * 256) * HF;
        #pragma unroll 4
        for (int i = 0; i < 256; ++i) {
            float xv = sh[i];
            a0 += xv * wp[(size_t)i * HF + t];
            a1 += xv * wp[(size_t)i * HF + t + 256];
        }
        float* dst = whv2 + (size_t)(kh * BB + b) * HF;
        dst[t] = a0; dst[t + 256] = a1;
        whs[t] = a0; whs[256 + t] = a1;
        __syncthreads();
        if (t < 8) {
            const float* as = a_src + t * FF;
            const float* ad = a_dst + t * FF;
            const float* wr = whs + t * FF;
            float s = 0.f;
            #pragma unroll 8
            for (int f = 0; f < FF; ++f) s += wr[f] * (as[f] + ad[f]);
            bvp[kh * 64 + b * 8 + t] = s;
        }
    } else if (bx < 784) {
        int id = bx - 528;
        int i = id * 4 + (t >> 6), lane = t & 63;
        int base = 0;
        for (int c = 0; c < 16; ++c) {
            int j = c * 64 + lane;
            bool pres = adj[(size_t)i * NN + j] > 0.f;
            unsigned long long m = __ballot(pres);
            int pos = __popcll(m & ((1ull << lane) - 1ull));
            if (pres) list[i * NN + base + pos] = j;
            base += __popcll(m);
        }
        if (lane == 0) cnt[i] = base;
    } else {
        float4 z; z.x = 0.f; z.y = 0.f; z.z = 0.f; z.w = 0.f;
        float4* oo = (float4*)outp;
        #pragma unroll
        for (int q = 0; q < 4; ++q) oo[q * 256 + t] = z;
    }
}

// ---------------- K2: attention — edl-staged exp phase, wave-parallel k C-loop
__global__ void __launch_bounds__(256) k_attn(
    const ushortT* __restrict__ whb, const float* __restrict__ whv2,
    const float* __restrict__ es, const float* __restrict__ ed,
    const float* __restrict__ edT, const float* __restrict__ bvp,
    const int* __restrict__ list, const int* __restrict__ cnt,
    const float* __restrict__ pool_q,
    ushortT* __restrict__ xoutb, float* __restrict__ sch)
{
    int i = blockIdx.x, z = blockIdx.y, t = threadIdx.x;
    int nn = cnt[i];

    __shared__ float att[KT * 32];     // 16 KB; reused as merge buffer
    __shared__ int jl[KT];
    __shared__ float edl_red[KT * 4];  // edl (KT*4) during chunks; red (8*32) after
    __shared__ float base_s[32], M_s[32], inv_s[32];
    __shared__ float edmax_z[4];

    // prologue: per-head global ed max
    {
        int hl = t >> 6, h = z * 4 + hl;
        const float* col = edT + h * NN;
        float m = -1e30f;
        #pragma unroll
        for (int g = 0; g < 16; ++g) m = fmaxf(m, col[(t & 63) + g * 64]);
        #pragma unroll
        for (int off = 32; off > 0; off >>= 1) m = fmaxf(m, __shfl_down(m, off));
        if ((t & 63) == 0) edmax_z[hl] = m;
    }
    __syncthreads();
    if (t < 32) {
        int hl = t >> 3, b = t & 7, h = z * 4 + hl;
        float base = es[i * HH + h] + bvp[b * 8 + h] + bvp[64 + b * 8 + h];
        base_s[t] = base;
        float mv = base + edmax_z[hl];       // >= any neighbor pre-leaky e
        M_s[t] = mv > 0.f ? mv : 0.2f * mv;  // leaky monotone -> valid upper bound
    }
    __syncthreads();

    int p = t & 31;
    float basev = base_s[p], Mv = M_s[p];
    float ssum = 0.f;

    int wid = t >> 6, tf = t & 63;
    int f0 = z * 256 + 4 * tf;         // 4 consecutive feats, same head
    int hl8 = (tf >> 4) * 8;           // head-local * 8
    float ac[32];                      // ac[f*8+b]
    #pragma unroll
    for (int q = 0; q < 32; ++q) ac[q] = 0.f;

    for (int c0 = 0; c0 < nn; c0 += KT) {
        int kc = min(KT, nn - c0);
        __syncthreads();               // protect att/jl/edl reuse
        if (t < kc) {
            int jv = list[(size_t)i * NN + c0 + t];
            jl[t] = jv;
            float4 v = *(const float4*)&ed[(size_t)jv * HH + z * 4];
            *(float4*)&edl_red[t * 4] = v;
        }
        __syncthreads();
        // exp phase: pure LDS + exp
        for (int k = t >> 5; k < kc; k += 8) {
            float e = basev + edl_red[(k << 2) + (p >> 3)];
            e = e > 0.f ? e : 0.2f * e;
            float pe = __expf(e - Mv);
            ssum += pe;
            att[k * 32 + p] = pe;
        }
        __syncthreads();
        #pragma unroll 2
        for (int k = wid; k < kc; k += 4) {
            int row = jl[k];
            const ushort4 u = *(const ushort4*)&whb[(size_t)row * HF + f0];
            float r0 = bf2f_u(u.x), r1 = bf2f_u(u.y);
            float r2 = bf2f_u(u.z), r3 = bf2f_u(u.w);
            const float4 aA = *(const float4*)&att[k * 32 + hl8];
            const float4 aB = *(const float4*)&att[k * 32 + hl8 + 4];
            ac[0]  += aA.x * r0; ac[8]  += aA.x * r1; ac[16] += aA.x * r2; ac[24] += aA.x * r3;
            ac[1]  += aA.y * r0; ac[9]  += aA.y * r1; ac[17] += aA.y * r2; ac[25] += aA.y * r3;
            ac[2]  += aA.z * r0; ac[10] += aA.z * r1; ac[18] += aA.z * r2; ac[26] += aA.z * r3;
            ac[3]  += aA.w * r0; ac[11] += aA.w * r1; ac[19] += aA.w * r2; ac[27] += aA.w * r3;
            ac[4]  += aB.x * r0; ac[12] += aB.x * r1; ac[20] += aB.x * r2; ac[28] += aB.x * r3;
            ac[5]  += aB.y * r0; ac[13] += aB.y * r1; ac[21] += aB.y * r2; ac[29] += aB.y * r3;
            ac[6]  += aB.z * r0; ac[14] += aB.z * r1; ac[22] += aB.z * r2; ac[30] += aB.z * r3;
            ac[7]  += aB.w * r0; ac[15] += aB.w * r1; ac[23] += aB.w * r2; ac[31] += aB.w * r3;
        }
    }

    // ---- reductions: softmax sums + 4-way accumulator merge (conflict-free layout) ----
    __syncthreads();                   // all att/edl reads done
    float* red = edl_red;              // reuse as red[8][32]
    red[(t >> 5) * 32 + p] = ssum;
    float* mrg = att;                  // mrg[q*64+tf]: lanes hit consecutive banks
    if (wid == 3) {
        #pragma unroll
        for (int q = 0; q < 32; ++q) mrg[q * 64 + tf] = ac[q];
    }
    __syncthreads();
    if (t < 32) {
        float s = 0.f;
        #pragma unroll
        for (int g = 0; g < 8; ++g) s += red[g * 32 + t];
        inv_s[t] = 1.0f / s;
    }
    if (wid == 2) {
        #pragma unroll
        for (int q = 0; q < 32; ++q) mrg[q * 64 + tf] += ac[q];
    }
    __syncthreads();
    if (wid == 1) {
        #pragma unroll
        for (int q = 0; q < 32; ++q) mrg[q * 64 + tf] += ac[q];
    }
    __syncthreads();

    if (wid == 0) {
        #pragma unroll
        for (int q = 0; q < 32; ++q) ac[q] += mrg[q * 64 + tf];
        int hl = tf >> 4;
        const float4 pq4 = *(const float4*)&pool_q[f0];
        #pragma unroll
        for (int b = 0; b < BB; ++b) {
            float iv = inv_s[hl * 8 + b];
            const float4 wva = *(const float4*)&whv2[(size_t)b * HF + f0];
            const float4 wvb = *(const float4*)&whv2[(size_t)(BB + b) * HF + f0];
            float o0 = ac[b]      * iv + wva.x + wvb.x;
            float o1 = ac[8 + b]  * iv + wva.y + wvb.y;
            float o2 = ac[16 + b] * iv + wva.z + wvb.z;
            float o3 = ac[24 + b] * iv + wva.w + wvb.w;
            o0 = o0 > 0.f ? o0 : (__expf(o0) - 1.f);
            o1 = o1 > 0.f ? o1 : (__expf(o1) - 1.f);
            o2 = o2 > 0.f ? o2 : (__expf(o2) - 1.f);
            o3 = o3 > 0.f ? o3 : (__expf(o3) - 1.f);
            ushort4 ov;
            ov.x = f2bf(o0); ov.y = f2bf(o1); ov.z = f2bf(o2); ov.w = f2bf(o3);
            *(ushort4*)&xoutb[((size_t)b * NN + i) * HF + f0] = ov;
            float sp = o0 * pq4.x + o1 * pq4.y + o2 * pq4.z + o3 * pq4.w;
            #pragma unroll
            for (int off = 32; off > 0; off >>= 1) sp += __shfl_down(sp, off);
            if (t == 0) sch[(z * BB + b) * NN + i] = sp;
        }
    }
}

// ---------------- K3: fused node softmax + pool + FC partial (32 x 16-feat slices)
__global__ void __launch_bounds__(256) k_tail(const float* __restrict__ sch,
    const ushortT* __restrict__ xoutb, const float* __restrict__ fcW,
    const float* __restrict__ fcb, float* __restrict__ out)
{
    int q = blockIdx.x, b = blockIdx.y, t = threadIdx.x;
    int lane = t & 63, wid = t >> 6;
    __shared__ float red[4];
    __shared__ float sM, sI;
    __shared__ float wl[NN];
    __shared__ float part[16][16];
    __shared__ float pl[16];

    float v[4], e[4];
    float mx = -1e30f;
    #pragma unroll
    for (int qq = 0; qq < 4; ++qq) {
        int n = qq * 256 + t;
        v[qq] = sch[b * NN + n] + sch[(BB + b) * NN + n];
        mx = fmaxf(mx, v[qq]);
    }
    #pragma unroll
    for (int off = 32; off > 0; off >>= 1) mx = fmaxf(mx, __shfl_down(mx, off));
    if (lane == 0) red[wid] = mx;
    __syncthreads();
    if (t == 0) sM = fmaxf(fmaxf(red[0], red[1]), fmaxf(red[2], red[3]));
    __syncthreads();
    float sMv = sM;
    float sm = 0.f;
    #pragma unroll
    for (int qq = 0; qq < 4; ++qq) { e[qq] = __expf(v[qq] - sMv); sm += e[qq]; }
    #pragma unroll
    for (int off = 32; off > 0; off >>= 1) sm += __shfl_down(sm, off);
    __syncthreads();
    if (lane == 0) red[wid] = sm;
    __syncthreads();
    if (t == 0) sI = 1.0f / (red[0] + red[1] + red[2] + red[3]);
    __syncthreads();
    float sIv = sI;
    #pragma unroll
    for (int qq = 0; qq < 4; ++qq) wl[qq * 256 + t] = e[qq] * sIv;
    __syncthreads();

    // pool feature-slice q (16 feats) over all nodes: fl = t&15, node-group ng = t>>4
    int fl = t & 15, ng = t >> 4;
    const ushortT* xb = xoutb + (size_t)b * NN * HF + q * 16 + fl;
    float acc0 = 0.f, acc1 = 0.f;
    #pragma unroll 8
    for (int n0 = 0; n0 < NN; n0 += 32) {
        int na = n0 + ng, nb2 = n0 + 16 + ng;
        acc0 += wl[na]  * bf2f_u(xb[(size_t)na  * HF]);
        acc1 += wl[nb2] * bf2f_u(xb[(size_t)nb2 * HF]);
    }
    part[ng][fl] = acc0 + acc1;
    __syncthreads();
    if (t < 16) {
        float s = 0.f;
        #pragma unroll
        for (int g = 0; g < 16; ++g) s += part[g][t];
        pl[t] = s;
    }
    __syncthreads();

    // FC partial: fcW rows q*16..q*16+15
    int f0 = 2 * t;
    float ax = 0.f, ay = 0.f;
    if (q == 0) { ax = fcb[f0]; ay = fcb[f0 + 1]; }
    #pragma unroll
    for (int kk = 0; kk < 16; ++kk) {
        float pv = pl[kk];
        const float2 w2 = *(const float2*)&fcW[(size_t)(q * 16 + kk) * HF + f0];
        ax += pv * w2.x; ay += pv * w2.y;
    }
    atomicAdd(&out[b * HF + f0], ax);
    atomicAdd(&out[b * HF + f0 + 1], ay);
}

extern "C" void kernel_launch(void* const* d_in, const int* in_sizes, int n_in,
                              void* d_out, int out_size, void* d_ws, size_t ws_size,
                              hipStream_t stream) {
    const float* vis   = (const float*)d_in[0];
    const float* lab   = (const float*)d_in[1];
    const float* adj   = (const float*)d_in[2];
    const float* Wm    = (const float*)d_in[3];
    const float* a_src = (const float*)d_in[4];
    const float* a_dst = (const float*)d_in[5];
    const float* pq    = (const float*)d_in[6];
    const float* fcW   = (const float*)d_in[7];
    const float* fcb   = (const float*)d_in[8];
    float* out = (float*)d_out;

    char* w = (char*)d_ws;
    ushortT* whb  = (ushortT*)w; w += (size_t)NN * HF * 2;      // 1 MB (bf16)
    float* whv2   = (float*)w;   w += (size_t)2 * BB * HF * 4;  // 32 KB
    float* bvp    = (float*)w;   w += 2 * 64 * 4;
    float* es     = (float*)w;   w += (size_t)NN * HH * 4;
    float* ed     = (float*)w;   w += (size_t)NN * HH * 4;
    float* edT    = (float*)w;   w += (size_t)HH * NN * 4;
    int*   nlist  = (int*)w;     w += (size_t)NN * NN * 4;      // 4 MB
    int*   ncnt   = (int*)w;     w += (size_t)NN * 4;
    ushortT* xoutb = (ushortT*)w; w += (size_t)BB * NN * HF * 2; // 8 MB (bf16)
    float* sch    = (float*)w;   w += (size_t)2 * BB * NN * 4;  // 64 KB

    k_prep<<<785, 256, 0, stream>>>(lab, vis, adj, Wm, a_src, a_dst,
                                    whb, whv2, bvp, es, ed, edT, nlist, ncnt, out);
    k_attn<<<dim3(NN, 2), 256, 0, stream>>>(whb, whv2, es, ed, edT, bvp,
                                            nlist, ncnt, pq, xoutb, sch);
    k_tail<<<dim3(32, BB), 256, 0, stream>>>(sch, xoutb, fcW, fcb, out);
}

// Round 21
// 65.124 us; speedup vs baseline: 1.2157x; 1.0499x over previous
//
#include <hip/hip_runtime.h>
#include <hip/hip_bf16.h>

#define NN 1024
#define BB 8
#define HH 8
#define FF 64
#define HF 512
#define KT 128

typedef unsigned short ushortT;

__device__ __forceinline__ ushortT f2bf(float f) {
    __hip_bfloat16 h = __float2bfloat16(f);
    return *(ushortT*)&h;
}
__device__ __forceinline__ float bf2f_u(ushortT u) {
    return __uint_as_float((unsigned)u << 16);
}

// ---------------- K1: fused prep (785 blocks)
//  bx 0..511  : wh GEMM full-K (4 nodes x 256-col half) + es/ed/edT epilogue
//  bx 512..527: whv2 K-half partials + bv partials
//  bx 528..783: adjacency compaction (4 rows/block)
//  bx 784     : zero out
__global__ void __launch_bounds__(256) k_prep(
    const float* __restrict__ lab, const float* __restrict__ vis,
    const float* __restrict__ adj, const float* __restrict__ Wm,
    const float* __restrict__ a_src, const float* __restrict__ a_dst,
    ushortT* __restrict__ whb, float* __restrict__ whv2, float* __restrict__ bvp,
    float* __restrict__ es, float* __restrict__ ed, float* __restrict__ edT,
    int* __restrict__ list, int* __restrict__ cnt, float* __restrict__ outp)
{
    int bx = blockIdx.x, t = threadIdx.x;
    __shared__ float sh[1024];
    __shared__ float whs[1024];
    if (bx < 512) {
        int np = bx >> 1, ch = bx & 1, n0 = np * 4;
        #pragma unroll
        for (int nd = 0; nd < 4; ++nd)
            sh[nd * 256 + t] = lab[(n0 + nd) * 256 + t];
        __syncthreads();
        float a0 = 0.f, a1 = 0.f, a2 = 0.f, a3 = 0.f;
        const float* wp = Wm + ch * 256 + t;
        #pragma unroll 8
        for (int i = 0; i < 256; ++i) {
            float w = wp[(size_t)i * HF];
            a0 += sh[i] * w;
            a1 += sh[256 + i] * w;
            a2 += sh[512 + i] * w;
            a3 += sh[768 + i] * w;
        }
        int cb = ch * 256 + t;
        whb[(size_t)(n0 + 0) * HF + cb] = f2bf(a0);
        whb[(size_t)(n0 + 1) * HF + cb] = f2bf(a1);
        whb[(size_t)(n0 + 2) * HF + cb] = f2bf(a2);
        whb[(size_t)(n0 + 3) * HF + cb] = f2bf(a3);
        whs[t] = a0; whs[256 + t] = a1; whs[512 + t] = a2; whs[768 + t] = a3;
        __syncthreads();
        if (t < 32) {
            int nd = t >> 3, rest = t & 7, hl = rest >> 1, sd = rest & 1;
            int h = ch * 4 + hl;
            const float* av = (sd ? a_dst : a_src) + h * FF;
            const float* wr = whs + nd * 256 + hl * FF;
            float s = 0.f;
            #pragma unroll
            for (int f = 0; f < FF; ++f) s += wr[f] * av[f];
            int n = n0 + nd;
            if (sd) { ed[n * HH + h] = s; edT[h * NN + n] = s; }
            else es[n * HH + h] = s;
        }
    } else if (bx < 528) {
        int id = bx - 512, b = id >> 1, kh = id & 1;
        if (t < 256) sh[t] = vis[b * 512 + kh * 256 + t];
        __syncthreads();
        float a0 = 0.f, a1 = 0.f;
        const float* wp = Wm + (size_t)(256 + kh * 256) * HF;
        #pragma unroll 4
        for (int i = 0; i < 256; ++i) {
            float xv = sh[i];
            a0 += xv * wp[(size_t)i * HF + t];
            a1 += xv * wp[(size_t)i * HF + t + 256];
        }
        float* dst = whv2 + (size_t)(kh * BB + b) * HF;
        dst[t] = a0; dst[t + 256] = a1;
        whs[t] = a0; whs[256 + t] = a1;
        __syncthreads();
        if (t < 8) {
            const float* as = a_src + t * FF;
            const float* ad = a_dst + t * FF;
            const float* wr = whs + t * FF;
            float s = 0.f;
            #pragma unroll 8
            for (int f = 0; f < FF; ++f) s += wr[f] * (as[f] + ad[f]);
            bvp[kh * 64 + b * 8 + t] = s;
        }
    } else if (bx < 784) {
        int id = bx - 528;
        int i = id * 4 + (t >> 6), lane = t & 63;
        int base = 0;
        for (int c = 0; c < 16; ++c) {
            int j = c * 64 + lane;
            bool pres = adj[(size_t)i * NN + j] > 0.f;
            unsigned long long m = __ballot(pres);
            int pos = __popcll(m & ((1ull << lane) - 1ull));
            if (pres) list[i * NN + base + pos] = j;
            base += __popcll(m);
        }
        if (lane == 0) cnt[i] = base;
    } else {
        float4 z; z.x = 0.f; z.y = 0.f; z.z = 0.f; z.w = 0.f;
        float4* oo = (float4*)outp;
        #pragma unroll
        for (int q = 0; q < 4; ++q) oo[q * 256 + t] = z;
    }
}

// ---------------- K2: attention — edl-staged exp, wave-parallel k, 4-wave epilogue
__global__ void __launch_bounds__(256) k_attn(
    const ushortT* __restrict__ whb, const float* __restrict__ whv2,
    const float* __restrict__ es, const float* __restrict__ ed,
    const float* __restrict__ edT, const float* __restrict__ bvp,
    const int* __restrict__ list, const int* __restrict__ cnt,
    const float* __restrict__ pool_q,
    ushortT* __restrict__ xoutb, float* __restrict__ sch)
{
    int i = blockIdx.x, z = blockIdx.y, t = threadIdx.x;
    int nn = cnt[i];

    __shared__ float att[KT * 32];     // 16 KB; reused as merge buffer
    __shared__ int jl[KT];
    __shared__ float edl_red[KT * 4];  // edl (KT*4) during chunks; red (8*32) after
    __shared__ float base_s[32], M_s[32], inv_s[32];
    __shared__ float edmax_z[4];

    // prologue: per-head global ed max (one float4 per lane covers the column)
    {
        int hl = t >> 6, h = z * 4 + hl;
        const float4* col4 = (const float4*)(edT + h * NN);
        float4 v = col4[t & 63];
        float m = fmaxf(fmaxf(v.x, v.y), fmaxf(v.z, v.w));
        #pragma unroll
        for (int off = 32; off > 0; off >>= 1) m = fmaxf(m, __shfl_down(m, off));
        if ((t & 63) == 0) edmax_z[hl] = m;
    }
    __syncthreads();
    if (t < 32) {
        int hl = t >> 3, b = t & 7, h = z * 4 + hl;
        float base = es[i * HH + h] + bvp[b * 8 + h] + bvp[64 + b * 8 + h];
        base_s[t] = base;
        float mv = base + edmax_z[hl];       // >= any neighbor pre-leaky e
        M_s[t] = mv > 0.f ? mv : 0.2f * mv;  // leaky monotone -> valid upper bound
    }
    __syncthreads();

    int p = t & 31;
    float basev = base_s[p], Mv = M_s[p];
    float ssum = 0.f;

    int wid = t >> 6, tf = t & 63;
    int f0 = z * 256 + 4 * tf;         // 4 consecutive feats, same head
    int hl8 = (tf >> 4) * 8;           // head-local * 8
    float ac[32];                      // ac[f*8+b]
    #pragma unroll
    for (int q = 0; q < 32; ++q) ac[q] = 0.f;

    for (int c0 = 0; c0 < nn; c0 += KT) {
        int kc = min(KT, nn - c0);
        __syncthreads();               // protect att/jl/edl reuse
        if (t < kc) {
            int jv = list[(size_t)i * NN + c0 + t];
            jl[t] = jv;
            float4 v = *(const float4*)&ed[(size_t)jv * HH + z * 4];
            *(float4*)&edl_red[t * 4] = v;
        }
        __syncthreads();
        // exp phase: pure LDS + exp
        for (int k = t >> 5; k < kc; k += 8) {
            float e = basev + edl_red[(k << 2) + (p >> 3)];
            e = e > 0.f ? e : 0.2f * e;
            float pe = __expf(e - Mv);
            ssum += pe;
            att[k * 32 + p] = pe;
        }
        __syncthreads();
        #pragma unroll 2
        for (int k = wid; k < kc; k += 4) {
            int row = jl[k];
            const ushort4 u = *(const ushort4*)&whb[(size_t)row * HF + f0];
            float r0 = bf2f_u(u.x), r1 = bf2f_u(u.y);
            float r2 = bf2f_u(u.z), r3 = bf2f_u(u.w);
            const float4 aA = *(const float4*)&att[k * 32 + hl8];
            const float4 aB = *(const float4*)&att[k * 32 + hl8 + 4];
            ac[0]  += aA.x * r0; ac[8]  += aA.x * r1; ac[16] += aA.x * r2; ac[24] += aA.x * r3;
            ac[1]  += aA.y * r0; ac[9]  += aA.y * r1; ac[17] += aA.y * r2; ac[25] += aA.y * r3;
            ac[2]  += aA.z * r0; ac[10] += aA.z * r1; ac[18] += aA.z * r2; ac[26] += aA.z * r3;
            ac[3]  += aA.w * r0; ac[11] += aA.w * r1; ac[19] += aA.w * r2; ac[27] += aA.w * r3;
            ac[4]  += aB.x * r0; ac[12] += aB.x * r1; ac[20] += aB.x * r2; ac[28] += aB.x * r3;
            ac[5]  += aB.y * r0; ac[13] += aB.y * r1; ac[21] += aB.y * r2; ac[29] += aB.y * r3;
            ac[6]  += aB.z * r0; ac[14] += aB.z * r1; ac[22] += aB.z * r2; ac[30] += aB.z * r3;
            ac[7]  += aB.w * r0; ac[15] += aB.w * r1; ac[23] += aB.w * r2; ac[31] += aB.w * r3;
        }
    }

    // ---- reductions: softmax sums + FULL 4-way merge into LDS (conflict-free) ----
    __syncthreads();                   // all att/edl reads done
    float* red = edl_red;              // reuse as red[8][32]
    red[(t >> 5) * 32 + p] = ssum;
    float* mrg = att;                  // mrg[q*64+tf]: lanes hit consecutive banks
    if (wid == 3) {
        #pragma unroll
        for (int q = 0; q < 32; ++q) mrg[q * 64 + tf] = ac[q];
    }
    __syncthreads();
    if (t < 32) {
        float s = 0.f;
        #pragma unroll
        for (int g = 0; g < 8; ++g) s += red[g * 32 + t];
        inv_s[t] = 1.0f / s;
    }
    if (wid == 2) {
        #pragma unroll
        for (int q = 0; q < 32; ++q) mrg[q * 64 + tf] += ac[q];
    }
    __syncthreads();
    if (wid == 1) {
        #pragma unroll
        for (int q = 0; q < 32; ++q) mrg[q * 64 + tf] += ac[q];
    }
    __syncthreads();
    if (wid == 0) {
        #pragma unroll
        for (int q = 0; q < 32; ++q) mrg[q * 64 + tf] += ac[q];
    }
    __syncthreads();

    // ---- epilogue: each wave finalizes its 2 batches from LDS ----
    {
        int hl = tf >> 4;
        const float4 pq4 = *(const float4*)&pool_q[f0];
        #pragma unroll
        for (int bb = 0; bb < 2; ++bb) {
            int b = wid * 2 + bb;
            float iv = inv_s[hl * 8 + b];
            const float4 wva = *(const float4*)&whv2[(size_t)b * HF + f0];
            const float4 wvb = *(const float4*)&whv2[(size_t)(BB + b) * HF + f0];
            float o0 = mrg[(b)      * 64 + tf] * iv + wva.x + wvb.x;
            float o1 = mrg[(8 + b)  * 64 + tf] * iv + wva.y + wvb.y;
            float o2 = mrg[(16 + b) * 64 + tf] * iv + wva.z + wvb.z;
            float o3 = mrg[(24 + b) * 64 + tf] * iv + wva.w + wvb.w;
            o0 = o0 > 0.f ? o0 : (__expf(o0) - 1.f);
            o1 = o1 > 0.f ? o1 : (__expf(o1) - 1.f);
            o2 = o2 > 0.f ? o2 : (__expf(o2) - 1.f);
            o3 = o3 > 0.f ? o3 : (__expf(o3) - 1.f);
            ushort4 ov;
            ov.x = f2bf(o0); ov.y = f2bf(o1); ov.z = f2bf(o2); ov.w = f2bf(o3);
            *(ushort4*)&xoutb[((size_t)b * NN + i) * HF + f0] = ov;
            float sp = o0 * pq4.x + o1 * pq4.y + o2 * pq4.z + o3 * pq4.w;
            #pragma unroll
            for (int off = 32; off > 0; off >>= 1) sp += __shfl_down(sp, off);
            if (tf == 0) sch[(z * BB + b) * NN + i] = sp;
        }
    }
}

// ---------------- K3: fused node softmax + pool + FC partial (32 x 16-feat slices)
__global__ void __launch_bounds__(256) k_tail(const float* __restrict__ sch,
    const ushortT* __restrict__ xoutb, const float* __restrict__ fcW,
    const float* __restrict__ fcb, float* __restrict__ out)
{
    int q = blockIdx.x, b = blockIdx.y, t = threadIdx.x;
    int lane = t & 63, wid = t >> 6;
    __shared__ float red[4];
    __shared__ float sM, sI;
    __shared__ float wl[NN];
    __shared__ float part[16][16];
    __shared__ float pl[16];

    float v[4], e[4];
    float mx = -1e30f;
    #pragma unroll
    for (int qq = 0; qq < 4; ++qq) {
        int n = qq * 256 + t;
        v[qq] = sch[b * NN + n] + sch[(BB + b) * NN + n];
        mx = fmaxf(mx, v[qq]);
    }
    #pragma unroll
    for (int off = 32; off > 0; off >>= 1) mx = fmaxf(mx, __shfl_down(mx, off));
    if (lane == 0) red[wid] = mx;
    __syncthreads();
    if (t == 0) sM = fmaxf(fmaxf(red[0], red[1]), fmaxf(red[2], red[3]));
    __syncthreads();
    float sMv = sM;
    float sm = 0.f;
    #pragma unroll
    for (int qq = 0; qq < 4; ++qq) { e[qq] = __expf(v[qq] - sMv); sm += e[qq]; }
    #pragma unroll
    for (int off = 32; off > 0; off >>= 1) sm += __shfl_down(sm, off);
    __syncthreads();
    if (lane == 0) red[wid] = sm;
    __syncthreads();
    if (t == 0) sI = 1.0f / (red[0] + red[1] + red[2] + red[3]);
    __syncthreads();
    float sIv = sI;
    #pragma unroll
    for (int qq = 0; qq < 4; ++qq) wl[qq * 256 + t] = e[qq] * sIv;
    __syncthreads();

    // pool feature-slice q (16 feats) over all nodes: fl = t&15, node-group ng = t>>4
    int fl = t & 15, ng = t >> 4;
    const ushortT* xb = xoutb + (size_t)b * NN * HF + q * 16 + fl;
    float acc0 = 0.f, acc1 = 0.f;
    #pragma unroll 8
    for (int n0 = 0; n0 < NN; n0 += 32) {
        int na = n0 + ng, nb2 = n0 + 16 + ng;
        acc0 += wl[na]  * bf2f_u(xb[(size_t)na  * HF]);
        acc1 += wl[nb2] * bf2f_u(xb[(size_t)nb2 * HF]);
    }
    part[ng][fl] = acc0 + acc1;
    __syncthreads();
    if (t < 16) {
        float s = 0.f;
        #pragma unroll
        for (int g = 0; g < 16; ++g) s += part[g][t];
        pl[t] = s;
    }
    __syncthreads();

    // FC partial: fcW rows q*16..q*16+15
    int f0 = 2 * t;
    float ax = 0.f, ay = 0.f;
    if (q == 0) { ax = fcb[f0]; ay = fcb[f0 + 1]; }
    #pragma unroll
    for (int kk = 0; kk < 16; ++kk) {
        float pv = pl[kk];
        const float2 w2 = *(const float2*)&fcW[(size_t)(q * 16 + kk) * HF + f0];
        ax += pv * w2.x; ay += pv * w2.y;
    }
    atomicAdd(&out[b * HF + f0], ax);
    atomicAdd(&out[b * HF + f0 + 1], ay);
}

extern "C" void kernel_launch(void* const* d_in, const int* in_sizes, int n_in,
                              void* d_out, int out_size, void* d_ws, size_t ws_size,
                              hipStream_t stream) {
    const float* vis   = (const float*)d_in[0];
    const float* lab   = (const float*)d_in[1];
    const float* adj   = (const float*)d_in[2];
    const float* Wm    = (const float*)d_in[3];
    const float* a_src = (const float*)d_in[4];
    const float* a_dst = (const float*)d_in[5];
    const float* pq    = (const float*)d_in[6];
    const float* fcW   = (const float*)d_in[7];
    const float* fcb   = (const float*)d_in[8];
    float* out = (float*)d_out;

    char* w = (char*)d_ws;
    ushortT* whb  = (ushortT*)w; w += (size_t)NN * HF * 2;      // 1 MB (bf16)
    float* whv2   = (float*)w;   w += (size_t)2 * BB * HF * 4;  // 32 KB
    float* bvp    = (float*)w;   w += 2 * 64 * 4;
    float* es     = (float*)w;   w += (size_t)NN * HH * 4;
    float* ed     = (float*)w;   w += (size_t)NN * HH * 4;
    float* edT    = (float*)w;   w += (size_t)HH * NN * 4;
    int*   nlist  = (int*)w;     w += (size_t)NN * NN * 4;      // 4 MB
    int*   ncnt   = (int*)w;     w += (size_t)NN * 4;
    ushortT* xoutb = (ushortT*)w; w += (size_t)BB * NN * HF * 2; // 8 MB (bf16)
    float* sch    = (float*)w;   w += (size_t)2 * BB * NN * 4;  // 64 KB

    k_prep<<<785, 256, 0, stream>>>(lab, vis, adj, Wm, a_src, a_dst,
                                    whb, whv2, bvp, es, ed, edT, nlist, ncnt, out);
    k_attn<<<dim3(NN, 2), 256, 0, stream>>>(whb, whv2, es, ed, edT, bvp,
                                            nlist, ncnt, pq, xoutb, sch);
    k_tail<<<dim3(32, BB), 256, 0, stream>>>(sch, xoutb, fcW, fcb, out);
}

// Round 22
// 64.061 us; speedup vs baseline: 1.2358x; 1.0166x over previous
//
#include <hip/hip_runtime.h>
#include <hip/hip_bf16.h>

#define NN 1024
#define BB 8
#define HH 8
#define FF 64
#define HF 512
#define KT 128

typedef unsigned short ushortT;

__device__ __forceinline__ ushortT f2bf(float f) {
    __hip_bfloat16 h = __float2bfloat16(f);
    return *(ushortT*)&h;
}
__device__ __forceinline__ float bf2f_u(ushortT u) {
    return __uint_as_float((unsigned)u << 16);
}

// ---------------- K1: fused prep (785 blocks)
//  bx 0..511  : wh GEMM full-K (4 nodes x 256-col half) + es/ed/edT epilogue
//  bx 512..527: whv2 K-half partials + bv partials
//  bx 528..783: adjacency compaction (4 rows/block)
//  bx 784     : zero out
__global__ void __launch_bounds__(256) k_prep(
    const float* __restrict__ lab, const float* __restrict__ vis,
    const float* __restrict__ adj, const float* __restrict__ Wm,
    const float* __restrict__ a_src, const float* __restrict__ a_dst,
    ushortT* __restrict__ whb, float* __restrict__ whv2, float* __restrict__ bvp,
    float* __restrict__ es, float* __restrict__ ed, float* __restrict__ edT,
    int* __restrict__ list, int* __restrict__ cnt, float* __restrict__ outp)
{
    int bx = blockIdx.x, t = threadIdx.x;
    __shared__ float sh[1024];
    __shared__ float whs[1024];
    if (bx < 512) {
        int np = bx >> 1, ch = bx & 1, n0 = np * 4;
        #pragma unroll
        for (int nd = 0; nd < 4; ++nd)
            sh[nd * 256 + t] = lab[(n0 + nd) * 256 + t];
        __syncthreads();
        float a0 = 0.f, a1 = 0.f, a2 = 0.f, a3 = 0.f;
        const float* wp = Wm + ch * 256 + t;
        #pragma unroll 8
        for (int i = 0; i < 256; ++i) {
            float w = wp[(size_t)i * HF];
            a0 += sh[i] * w;
            a1 += sh[256 + i] * w;
            a2 += sh[512 + i] * w;
            a3 += sh[768 + i] * w;
        }
        int cb = ch * 256 + t;
        whb[(size_t)(n0 + 0) * HF + cb] = f2bf(a0);
        whb[(size_t)(n0 + 1) * HF + cb] = f2bf(a1);
        whb[(size_t)(n0 + 2) * HF + cb] = f2bf(a2);
        whb[(size_t)(n0 + 3) * HF + cb] = f2bf(a3);
        whs[t] = a0; whs[256 + t] = a1; whs[512 + t] = a2; whs[768 + t] = a3;
        __syncthreads();
        if (t < 32) {
            int nd = t >> 3, rest = t & 7, hl = rest >> 1, sd = rest & 1;
            int h = ch * 4 + hl;
            const float* av = (sd ? a_dst : a_src) + h * FF;
            const float* wr = whs + nd * 256 + hl * FF;
            float s = 0.f;
            #pragma unroll
            for (int f = 0; f < FF; ++f) s += wr[f] * av[f];
            int n = n0 + nd;
            if (sd) { ed[n * HH + h] = s; edT[h * NN + n] = s; }
            else es[n * HH + h] = s;
        }
    } else if (bx < 528) {
        int id = bx - 512, b = id >> 1, kh = id & 1;
        if (t < 256) sh[t] = vis[b * 512 + kh * 256 + t];
        __syncthreads();
        float a0 = 0.f, a1 = 0.f;
        const float* wp = Wm + (size_t)(256 + kh * 256) * HF;
        #pragma unroll 4
        for (int i = 0; i < 256; ++i) {
            float xv = sh[i];
            a0 += xv * wp[(size_t)i * HF + t];
            a1 += xv * wp[(size_t)i * HF + t + 256];
        }
        float* dst = whv2 + (size_t)(kh * BB + b) * HF;
        dst[t] = a0; dst[t + 256] = a1;
        whs[t] = a0; whs[256 + t] = a1;
        __syncthreads();
        if (t < 8) {
            const float* as = a_src + t * FF;
            const float* ad = a_dst + t * FF;
            const float* wr = whs + t * FF;
            float s = 0.f;
            #pragma unroll 8
            for (int f = 0; f < FF; ++f) s += wr[f] * (as[f] + ad[f]);
            bvp[kh * 64 + b * 8 + t] = s;
        }
    } else if (bx < 784) {
        int id = bx - 528;
        int i = id * 4 + (t >> 6), lane = t & 63;
        int base = 0;
        for (int c = 0; c < 16; ++c) {
            int j = c * 64 + lane;
            bool pres = adj[(size_t)i * NN + j] > 0.f;
            unsigned long long m = __ballot(pres);
            int pos = __popcll(m & ((1ull << lane) - 1ull));
            if (pres) list[i * NN + base + pos] = j;
            base += __popcll(m);
        }
        if (lane == 0) cnt[i] = base;
    } else {
        float4 z; z.x = 0.f; z.y = 0.f; z.z = 0.f; z.w = 0.f;
        float4* oo = (float4*)outp;
        #pragma unroll
        for (int q = 0; q < 4; ++q) oo[q * 256 + t] = z;
    }
}

// ---------------- K2: attention — edl-staged exp, wave-parallel k, 4-wave epilogue
__global__ void __launch_bounds__(256) k_attn(
    const ushortT* __restrict__ whb, const float* __restrict__ whv2,
    const float* __restrict__ es, const float* __restrict__ ed,
    const float* __restrict__ edT, const float* __restrict__ bvp,
    const int* __restrict__ list, const int* __restrict__ cnt,
    const float* __restrict__ pool_q,
    ushortT* __restrict__ xoutb, float* __restrict__ sch)
{
    int i = blockIdx.x, z = blockIdx.y, t = threadIdx.x;
    int nn = cnt[i];

    __shared__ float att[KT * 32];     // 16 KB; reused as merge buffer
    __shared__ int jl[KT];
    __shared__ float edl_red[KT * 4];  // edl (KT*4) during chunks; red (8*32) after
    __shared__ float base_s[32], M_s[32], inv_s[32];
    __shared__ float edmax_z[4];

    // prologue: per-head global ed max (one float4 per lane covers the column)
    {
        int hl = t >> 6, h = z * 4 + hl;
        const float4* col4 = (const float4*)(edT + h * NN);
        float4 v = col4[t & 63];
        float m = fmaxf(fmaxf(v.x, v.y), fmaxf(v.z, v.w));
        #pragma unroll
        for (int off = 32; off > 0; off >>= 1) m = fmaxf(m, __shfl_down(m, off));
        if ((t & 63) == 0) edmax_z[hl] = m;
    }
    __syncthreads();
    if (t < 32) {
        int hl = t >> 3, b = t & 7, h = z * 4 + hl;
        float base = es[i * HH + h] + bvp[b * 8 + h] + bvp[64 + b * 8 + h];
        base_s[t] = base;
        float mv = base + edmax_z[hl];       // >= any neighbor pre-leaky e
        M_s[t] = mv > 0.f ? mv : 0.2f * mv;  // leaky monotone -> valid upper bound
    }
    __syncthreads();

    int p = t & 31;
    float basev = base_s[p], Mv = M_s[p];
    float ssum = 0.f;

    int wid = t >> 6, tf = t & 63;
    int f0 = z * 256 + 4 * tf;         // 4 consecutive feats, same head
    int hl8 = (tf >> 4) * 8;           // head-local * 8
    float ac[32];                      // ac[f*8+b]
    #pragma unroll
    for (int q = 0; q < 32; ++q) ac[q] = 0.f;

    for (int c0 = 0; c0 < nn; c0 += KT) {
        int kc = min(KT, nn - c0);
        __syncthreads();               // protect att/jl/edl reuse
        if (t < kc) {
            int jv = list[(size_t)i * NN + c0 + t];
            jl[t] = jv;
            float4 v = *(const float4*)&ed[(size_t)jv * HH + z * 4];
            *(float4*)&edl_red[t * 4] = v;
        }
        __syncthreads();
        // exp phase: pure LDS + exp
        for (int k = t >> 5; k < kc; k += 8) {
            float e = basev + edl_red[(k << 2) + (p >> 3)];
            e = e > 0.f ? e : 0.2f * e;
            float pe = __expf(e - Mv);
            ssum += pe;
            att[k * 32 + p] = pe;
        }
        __syncthreads();
        #pragma unroll 3
        for (int k = wid; k < kc; k += 4) {
            int row = jl[k];
            const ushort4 u = *(const ushort4*)&whb[(size_t)row * HF + f0];
            float r0 = bf2f_u(u.x), r1 = bf2f_u(u.y);
            float r2 = bf2f_u(u.z), r3 = bf2f_u(u.w);
            const float4 aA = *(const float4*)&att[k * 32 + hl8];
            const float4 aB = *(const float4*)&att[k * 32 + hl8 + 4];
            ac[0]  += aA.x * r0; ac[8]  += aA.x * r1; ac[16] += aA.x * r2; ac[24] += aA.x * r3;
            ac[1]  += aA.y * r0; ac[9]  += aA.y * r1; ac[17] += aA.y * r2; ac[25] += aA.y * r3;
            ac[2]  += aA.z * r0; ac[10] += aA.z * r1; ac[18] += aA.z * r2; ac[26] += aA.z * r3;
            ac[3]  += aA.w * r0; ac[11] += aA.w * r1; ac[19] += aA.w * r2; ac[27] += aA.w * r3;
            ac[4]  += aB.x * r0; ac[12] += aB.x * r1; ac[20] += aB.x * r2; ac[28] += aB.x * r3;
            ac[5]  += aB.y * r0; ac[13] += aB.y * r1; ac[21] += aB.y * r2; ac[29] += aB.y * r3;
            ac[6]  += aB.z * r0; ac[14] += aB.z * r1; ac[22] += aB.z * r2; ac[30] += aB.z * r3;
            ac[7]  += aB.w * r0; ac[15] += aB.w * r1; ac[23] += aB.w * r2; ac[31] += aB.w * r3;
        }
    }

    // ---- reductions: softmax sums + FULL 4-way merge into LDS (conflict-free) ----
    __syncthreads();                   // all att/edl reads done
    float* red = edl_red;              // reuse as red[8][32]
    red[(t >> 5) * 32 + p] = ssum;
    float* mrg = att;                  // mrg[q*64+tf]: lanes hit consecutive banks
    if (wid == 3) {
        #pragma unroll
        for (int q = 0; q < 32; ++q) mrg[q * 64 + tf] = ac[q];
    }
    __syncthreads();
    if (t < 32) {
        float s = 0.f;
        #pragma unroll
        for (int g = 0; g < 8; ++g) s += red[g * 32 + t];
        inv_s[t] = 1.0f / s;
    }
    if (wid == 2) {
        #pragma unroll
        for (int q = 0; q < 32; ++q) mrg[q * 64 + tf] += ac[q];
    }
    __syncthreads();
    if (wid == 1) {
        #pragma unroll
        for (int q = 0; q < 32; ++q) mrg[q * 64 + tf] += ac[q];
    }
    __syncthreads();
    if (wid == 0) {
        #pragma unroll
        for (int q = 0; q < 32; ++q) mrg[q * 64 + tf] += ac[q];
    }
    __syncthreads();

    // ---- epilogue: each wave finalizes its 2 batches from LDS ----
    {
        int hl = tf >> 4;
        const float4 pq4 = *(const float4*)&pool_q[f0];
        #pragma unroll
        for (int bb = 0; bb < 2; ++bb) {
            int b = wid * 2 + bb;
            float iv = inv_s[hl * 8 + b];
            const float4 wva = *(const float4*)&whv2[(size_t)b * HF + f0];
            const float4 wvb = *(const float4*)&whv2[(size_t)(BB + b) * HF + f0];
            float o0 = mrg[(b)      * 64 + tf] * iv + wva.x + wvb.x;
            float o1 = mrg[(8 + b)  * 64 + tf] * iv + wva.y + wvb.y;
            float o2 = mrg[(16 + b) * 64 + tf] * iv + wva.z + wvb.z;
            float o3 = mrg[(24 + b) * 64 + tf] * iv + wva.w + wvb.w;
            o0 = o0 > 0.f ? o0 : (__expf(o0) - 1.f);
            o1 = o1 > 0.f ? o1 : (__expf(o1) - 1.f);
            o2 = o2 > 0.f ? o2 : (__expf(o2) - 1.f);
            o3 = o3 > 0.f ? o3 : (__expf(o3) - 1.f);
            ushort4 ov;
            ov.x = f2bf(o0); ov.y = f2bf(o1); ov.z = f2bf(o2); ov.w = f2bf(o3);
            *(ushort4*)&xoutb[((size_t)b * NN + i) * HF + f0] = ov;
            float sp = o0 * pq4.x + o1 * pq4.y + o2 * pq4.z + o3 * pq4.w;
            #pragma unroll
            for (int off = 32; off > 0; off >>= 1) sp += __shfl_down(sp, off);
            if (tf == 0) sch[(z * BB + b) * NN + i] = sp;
        }
    }
}

// ---------------- K3: fused node softmax + pool + FC partial (32 x 16-feat slices)
__global__ void __launch_bounds__(256) k_tail(const float* __restrict__ sch,
    const ushortT* __restrict__ xoutb, const float* __restrict__ fcW,
    const float* __restrict__ fcb, float* __restrict__ out)
{
    int q = blockIdx.x, b = blockIdx.y, t = threadIdx.x;
    int lane = t & 63, wid = t >> 6;
    __shared__ float red[4];
    __shared__ float sM, sI;
    __shared__ float wl[NN];
    __shared__ float part[16][16];
    __shared__ float pl[16];

    float v[4], e[4];
    float mx = -1e30f;
    #pragma unroll
    for (int qq = 0; qq < 4; ++qq) {
        int n = qq * 256 + t;
        v[qq] = sch[b * NN + n] + sch[(BB + b) * NN + n];
        mx = fmaxf(mx, v[qq]);
    }
    #pragma unroll
    for (int off = 32; off > 0; off >>= 1) mx = fmaxf(mx, __shfl_down(mx, off));
    if (lane == 0) red[wid] = mx;
    __syncthreads();
    if (t == 0) sM = fmaxf(fmaxf(red[0], red[1]), fmaxf(red[2], red[3]));
    __syncthreads();
    float sMv = sM;
    float sm = 0.f;
    #pragma unroll
    for (int qq = 0; qq < 4; ++qq) { e[qq] = __expf(v[qq] - sMv); sm += e[qq]; }
    #pragma unroll
    for (int off = 32; off > 0; off >>= 1) sm += __shfl_down(sm, off);
    __syncthreads();
    if (lane == 0) red[wid] = sm;
    __syncthreads();
    if (t == 0) sI = 1.0f / (red[0] + red[1] + red[2] + red[3]);
    __syncthreads();
    float sIv = sI;
    #pragma unroll
    for (int qq = 0; qq < 4; ++qq) wl[qq * 256 + t] = e[qq] * sIv;
    __syncthreads();

    // pool feature-slice q (16 feats) over all nodes: fl = t&15, node-group ng = t>>4
    int fl = t & 15, ng = t >> 4;
    const ushortT* xb = xoutb + (size_t)b * NN * HF + q * 16 + fl;
    float acc0 = 0.f, acc1 = 0.f;
    #pragma unroll 8
    for (int n0 = 0; n0 < NN; n0 += 32) {
        int na = n0 + ng, nb2 = n0 + 16 + ng;
        acc0 += wl[na]  * bf2f_u(xb[(size_t)na  * HF]);
        acc1 += wl[nb2] * bf2f_u(xb[(size_t)nb2 * HF]);
    }
    part[ng][fl] = acc0 + acc1;
    __syncthreads();
    if (t < 16) {
        float s = 0.f;
        #pragma unroll
        for (int g = 0; g < 16; ++g) s += part[g][t];
        pl[t] = s;
    }
    __syncthreads();

    // FC partial: fcW rows q*16..q*16+15
    int f0 = 2 * t;
    float ax = 0.f, ay = 0.f;
    if (q == 0) { ax = fcb[f0]; ay = fcb[f0 + 1]; }
    #pragma unroll
    for (int kk = 0; kk < 16; ++kk) {
        float pv = pl[kk];
        const float2 w2 = *(const float2*)&fcW[(size_t)(q * 16 + kk) * HF + f0];
        ax += pv * w2.x; ay += pv * w2.y;
    }
    atomicAdd(&out[b * HF + f0], ax);
    atomicAdd(&out[b * HF + f0 + 1], ay);
}

extern "C" void kernel_launch(void* const* d_in, const int* in_sizes, int n_in,
                              void* d_out, int out_size, void* d_ws, size_t ws_size,
                              hipStream_t stream) {
    const float* vis   = (const float*)d_in[0];
    const float* lab   = (const float*)d_in[1];
    const float* adj   = (const float*)d_in[2];
    const float* Wm    = (const float*)d_in[3];
    const float* a_src = (const float*)d_in[4];
    const float* a_dst = (const float*)d_in[5];
    const float* pq    = (const float*)d_in[6];
    const float* fcW   = (const float*)d_in[7];
    const float* fcb   = (const float*)d_in[8];
    float* out = (float*)d_out;

    char* w = (char*)d_ws;
    ushortT* whb  = (ushortT*)w; w += (size_t)NN * HF * 2;      // 1 MB (bf16)
    float* whv2   = (float*)w;   w += (size_t)2 * BB * HF * 4;  // 32 KB
    float* bvp    = (float*)w;   w += 2 * 64 * 4;
    float* es     = (float*)w;   w += (size_t)NN * HH * 4;
    float* ed     = (float*)w;   w += (size_t)NN * HH * 4;
    float* edT    = (float*)w;   w += (size_t)HH * NN * 4;
    int*   nlist  = (int*)w;     w += (size_t)NN * NN * 4;      // 4 MB
    int*   ncnt   = (int*)w;     w += (size_t)NN * 4;
    ushortT* xoutb = (ushortT*)w; w += (size_t)BB * NN * HF * 2; // 8 MB (bf16)
    float* sch    = (float*)w;   w += (size_t)2 * BB * NN * 4;  // 64 KB

    k_prep<<<785, 256, 0, stream>>>(lab, vis, adj, Wm, a_src, a_dst,
                                    whb, whv2, bvp, es, ed, edT, nlist, ncnt, out);
    k_attn<<<dim3(NN, 2), 256, 0, stream>>>(whb, whv2, es, ed, edT, bvp,
                                            nlist, ncnt, pq, xoutb, sch);
    k_tail<<<dim3(32, BB), 256, 0, stream>>>(sch, xoutb, fcW, fcb, out);
}